// Round 6
// baseline (53.226 us; speedup 1.0000x reference)
//
#include <hip/hip_runtime.h>

// DCN cross net, algebraically unrolled (rounds 1-4). This round:
//  - persistent streaming kernel: 512 blocks x 4 waves, each wave handles 8
//    row-pairs grid-strided with a ping-pong double buffer (load pair i+1's x
//    while computing/storing pair i) -- mimics the 7.1 TB/s fill kernel's
//    "few waves, always-full memory queue" shape.
//  - weights/biases hoisted to registers once per wave; c-scalars via uniform
//    (scalar) loads. Steady-state loop = 8 x-loads + VALU + 8 stores only.

#define DCN_D 1024
#define DCN_F4 (DCN_D / 4)   // 256 float4 per row

// ws layout: ws[0..1023] = Bsum; ws[1024..1029] = {c01,c02,c12,c03,c13,c23}

__global__ __launch_bounds__(256) void dcn_pre_kernel(
    const float* __restrict__ w,   // [4, D]
    const float* __restrict__ b,   // [4, D]
    float* __restrict__ ws)
{
    const int t = threadIdx.x;
    for (int d = t; d < DCN_D; d += 256)
        ws[d] = b[d] + b[DCN_D + d] + b[2 * DCN_D + d] + b[3 * DCN_D + d];
    float p[6] = {0, 0, 0, 0, 0, 0};
    for (int d = t; d < DCN_D; d += 256) {
        const float b0 = b[d], b1 = b[DCN_D + d], b2 = b[2 * DCN_D + d];
        const float w1 = w[DCN_D + d], w2 = w[2 * DCN_D + d], w3 = w[3 * DCN_D + d];
        p[0] = fmaf(b0, w1, p[0]);
        p[1] = fmaf(b0, w2, p[1]);
        p[2] = fmaf(b1, w2, p[2]);
        p[3] = fmaf(b0, w3, p[3]);
        p[4] = fmaf(b1, w3, p[4]);
        p[5] = fmaf(b2, w3, p[5]);
    }
    __shared__ float red[6][4];
    const int wave = t >> 6, lane = t & 63;
    #pragma unroll
    for (int k = 0; k < 6; ++k) {
        float v = p[k];
        #pragma unroll
        for (int off = 32; off > 0; off >>= 1) v += __shfl_down(v, off, 64);
        if (lane == 0) red[k][wave] = v;
    }
    __syncthreads();
    if (t < 6) ws[DCN_D + t] = red[t][0] + red[t][1] + red[t][2] + red[t][3];
}

__global__ __launch_bounds__(256) void dcn_main_kernel(
    const float* __restrict__ x,
    const float* __restrict__ w,
    const float* __restrict__ ws,
    float* __restrict__ out,
    int B)
{
    const int wid  = (int)((blockIdx.x * blockDim.x + threadIdx.x) >> 6);
    const int lane = (int)(threadIdx.x & 63);
    const int nw   = (int)((gridDim.x * blockDim.x) >> 6);
    const int npairs = B >> 1;

    // hoist weights + biases into registers (one-time, L1/L2-served)
    const float4* __restrict__ w4  = reinterpret_cast<const float4*>(w);
    const float4* __restrict__ bs4 = reinterpret_cast<const float4*>(ws);
    float4 wv[4][4];   // [layer][j]
    float4 bv[4];
    #pragma unroll
    for (int j = 0; j < 4; ++j) {
        const int idx = lane + 64 * j;
        bv[j] = bs4[idx];
        #pragma unroll
        for (int l = 0; l < 4; ++l) wv[l][j] = w4[l * DCN_F4 + idx];
    }
    // uniform scalars (compiler emits s_load)
    const float c01   = ws[DCN_D + 0];
    const float c2sum = ws[DCN_D + 1] + ws[DCN_D + 2];
    const float c3sum = ws[DCN_D + 3] + ws[DCN_D + 4] + ws[DCN_D + 5];

    int pair = wid;
    if (pair >= npairs) return;

    float4 xa[2][4], xb[2][4];

#define LOADX(buf, pr) do {                                                          \
    const float4* __restrict__ _x0 =                                                 \
        reinterpret_cast<const float4*>(x + (size_t)(2 * (pr)) * DCN_D);             \
    const float4* __restrict__ _x1 =                                                 \
        reinterpret_cast<const float4*>(x + (size_t)(2 * (pr) + 1) * DCN_D);         \
    _Pragma("unroll")                                                                \
    for (int j = 0; j < 4; ++j) buf[0][j] = _x0[lane + 64 * j];                      \
    _Pragma("unroll")                                                                \
    for (int j = 0; j < 4; ++j) buf[1][j] = _x1[lane + 64 * j];                      \
} while (0)

#define COMPSTORE(buf, pr) do {                                                      \
    float p0[4] = {0, 0, 0, 0}, p1[4] = {0, 0, 0, 0};                                \
    _Pragma("unroll")                                                                \
    for (int j = 0; j < 4; ++j) {                                                    \
        _Pragma("unroll")                                                            \
        for (int l = 0; l < 4; ++l) {                                                \
            p0[l] = fmaf(buf[0][j].x, wv[l][j].x, fmaf(buf[0][j].y, wv[l][j].y,      \
                    fmaf(buf[0][j].z, wv[l][j].z,                                    \
                    fmaf(buf[0][j].w, wv[l][j].w, p0[l]))));                         \
            p1[l] = fmaf(buf[1][j].x, wv[l][j].x, fmaf(buf[1][j].y, wv[l][j].y,      \
                    fmaf(buf[1][j].z, wv[l][j].z,                                    \
                    fmaf(buf[1][j].w, wv[l][j].w, p1[l]))));                         \
        }                                                                            \
    }                                                                                \
    _Pragma("unroll")                                                                \
    for (int off = 1; off < 64; off <<= 1) {                                         \
        _Pragma("unroll")                                                            \
        for (int l = 0; l < 4; ++l) {                                                \
            p0[l] += __shfl_xor(p0[l], off, 64);                                     \
            p1[l] += __shfl_xor(p1[l], off, 64);                                     \
        }                                                                            \
    }                                                                                \
    const float t1a = 1.f + p0[0];                                                   \
    const float s1a = fmaf(p0[1], t1a, c01);                                         \
    const float t2a = t1a + s1a;                                                     \
    const float s2a = fmaf(p0[2], t2a, c2sum);                                       \
    const float t3a = t2a + s2a;                                                     \
    const float s3a = fmaf(p0[3], t3a, c3sum);                                       \
    const float S0  = t3a + s3a;                                                     \
    const float t1b = 1.f + p1[0];                                                   \
    const float s1b = fmaf(p1[1], t1b, c01);                                         \
    const float t2b = t1b + s1b;                                                     \
    const float s2b = fmaf(p1[2], t2b, c2sum);                                       \
    const float t3b = t2b + s2b;                                                     \
    const float s3b = fmaf(p1[3], t3b, c3sum);                                       \
    const float S1  = t3b + s3b;                                                     \
    float4* __restrict__ _o0 =                                                       \
        reinterpret_cast<float4*>(out + (size_t)(2 * (pr)) * DCN_D);                 \
    float4* __restrict__ _o1 =                                                       \
        reinterpret_cast<float4*>(out + (size_t)(2 * (pr) + 1) * DCN_D);             \
    _Pragma("unroll")                                                                \
    for (int j = 0; j < 4; ++j) {                                                    \
        const int idx = lane + 64 * j;                                               \
        float4 a;                                                                    \
        a.x = fmaf(buf[0][j].x, S0, bv[j].x);                                        \
        a.y = fmaf(buf[0][j].y, S0, bv[j].y);                                        \
        a.z = fmaf(buf[0][j].z, S0, bv[j].z);                                        \
        a.w = fmaf(buf[0][j].w, S0, bv[j].w);                                        \
        _o0[idx] = a;                                                                \
        float4 c;                                                                    \
        c.x = fmaf(buf[1][j].x, S1, bv[j].x);                                        \
        c.y = fmaf(buf[1][j].y, S1, bv[j].y);                                        \
        c.z = fmaf(buf[1][j].z, S1, bv[j].z);                                        \
        c.w = fmaf(buf[1][j].w, S1, bv[j].w);                                        \
        _o1[idx] = c;                                                                \
    }                                                                                \
} while (0)

    // ping-pong pipeline: load next pair's x while computing current pair
    LOADX(xa, pair);
    int nxt = pair + nw;
    #pragma unroll 1
    for (;;) {
        bool hn = nxt < npairs;
        if (hn) LOADX(xb, nxt);
        COMPSTORE(xa, pair);
        if (!hn) break;
        pair = nxt; nxt += nw;
        hn = nxt < npairs;
        if (hn) LOADX(xa, nxt);
        COMPSTORE(xb, pair);
        if (!hn) break;
        pair = nxt; nxt += nw;
    }
#undef LOADX
#undef COMPSTORE
}

extern "C" void kernel_launch(void* const* d_in, const int* in_sizes, int n_in,
                              void* d_out, int out_size, void* d_ws, size_t ws_size,
                              hipStream_t stream) {
    const float* x = (const float*)d_in[0];
    const float* w = (const float*)d_in[1];
    const float* b = (const float*)d_in[2];
    float* out = (float*)d_out;
    float* ws = (float*)d_ws;
    const int B = in_sizes[0] / DCN_D;

    dcn_pre_kernel<<<1, 256, 0, stream>>>(w, b, ws);
    // persistent streaming: 512 blocks (2/CU), 4 waves each -> 2048 waves,
    // 8 row-pairs per wave, grid-strided.
    dcn_main_kernel<<<512, 256, 0, stream>>>(x, w, ws, out, B);
}

// Round 7
// 52.586 us; speedup vs baseline: 1.0122x; 1.0122x over previous
//
#include <hip/hip_runtime.h>

// DCN cross net, algebraically unrolled (rounds 1-4). Round 6:
//  - 4 consecutive rows per wave, all 16 x-loads issued up-front (16 KB
//    in flight per wave, 2x round-4) -> more outstanding bytes per CU.
//  - bias hoisted (16 VGPR); weights RELOADED per pair from L1 (keeps VGPR
//    ~120 so 4-5 waves/SIMD survive -- round 5 showed hoisting weights is
//    zero-sum via occupancy).
//  - load order: bias + pair0-weights first, then all x rows -> pair-0
//    compute waits vmcnt(8) only (rows 2-3 still in flight), pair-0 stores
//    overlap rows 2-3 arrival (in-order vmcnt discipline).
//  - contiguous row ownership per wave, exact grid, regular stores.

#define DCN_D 1024
#define DCN_F4 (DCN_D / 4)   // 256 float4 per row

// ws layout: ws[0..1023] = Bsum; ws[1024..1029] = {c01,c02,c12,c03,c13,c23}

__global__ __launch_bounds__(256) void dcn_pre_kernel(
    const float* __restrict__ w,   // [4, D]
    const float* __restrict__ b,   // [4, D]
    float* __restrict__ ws)
{
    const int t = threadIdx.x;
    for (int d = t; d < DCN_D; d += 256)
        ws[d] = b[d] + b[DCN_D + d] + b[2 * DCN_D + d] + b[3 * DCN_D + d];
    float p[6] = {0, 0, 0, 0, 0, 0};
    for (int d = t; d < DCN_D; d += 256) {
        const float b0 = b[d], b1 = b[DCN_D + d], b2 = b[2 * DCN_D + d];
        const float w1 = w[DCN_D + d], w2 = w[2 * DCN_D + d], w3 = w[3 * DCN_D + d];
        p[0] = fmaf(b0, w1, p[0]);
        p[1] = fmaf(b0, w2, p[1]);
        p[2] = fmaf(b1, w2, p[2]);
        p[3] = fmaf(b0, w3, p[3]);
        p[4] = fmaf(b1, w3, p[4]);
        p[5] = fmaf(b2, w3, p[5]);
    }
    __shared__ float red[6][4];
    const int wave = t >> 6, lane = t & 63;
    #pragma unroll
    for (int k = 0; k < 6; ++k) {
        float v = p[k];
        #pragma unroll
        for (int off = 32; off > 0; off >>= 1) v += __shfl_down(v, off, 64);
        if (lane == 0) red[k][wave] = v;
    }
    __syncthreads();
    if (t < 6) ws[DCN_D + t] = red[t][0] + red[t][1] + red[t][2] + red[t][3];
}

// Compute S for two rows held in registers, then store out = x*S + Bsum.
// Weights are (re)loaded from L1 inside -- transient 16 VGPR.
__device__ __forceinline__ void dcn_pair(
    const float4 xa[4], const float4 xb[4],
    const float4* __restrict__ w4, const float4 bv[4],
    float c01, float c2sum, float c3sum,
    float* __restrict__ out, int rowA, int rowB, int lane)
{
    float p0[4] = {0, 0, 0, 0}, p1[4] = {0, 0, 0, 0};
    #pragma unroll
    for (int j = 0; j < 4; ++j) {
        const int idx = lane + 64 * j;
        #pragma unroll
        for (int l = 0; l < 4; ++l) {
            const float4 wv = w4[l * DCN_F4 + idx];   // L1-resident
            p0[l] = fmaf(xa[j].x, wv.x, fmaf(xa[j].y, wv.y,
                    fmaf(xa[j].z, wv.z, fmaf(xa[j].w, wv.w, p0[l]))));
            p1[l] = fmaf(xb[j].x, wv.x, fmaf(xb[j].y, wv.y,
                    fmaf(xb[j].z, wv.z, fmaf(xb[j].w, wv.w, p1[l]))));
        }
    }
    #pragma unroll
    for (int off = 1; off < 64; off <<= 1) {
        #pragma unroll
        for (int l = 0; l < 4; ++l) {
            p0[l] += __shfl_xor(p0[l], off, 64);
            p1[l] += __shfl_xor(p1[l], off, 64);
        }
    }
    const float t1a = 1.f + p0[0];
    const float s1a = fmaf(p0[1], t1a, c01);
    const float t2a = t1a + s1a;
    const float s2a = fmaf(p0[2], t2a, c2sum);
    const float t3a = t2a + s2a;
    const float s3a = fmaf(p0[3], t3a, c3sum);
    const float S0  = t3a + s3a;
    const float t1b = 1.f + p1[0];
    const float s1b = fmaf(p1[1], t1b, c01);
    const float t2b = t1b + s1b;
    const float s2b = fmaf(p1[2], t2b, c2sum);
    const float t3b = t2b + s2b;
    const float s3b = fmaf(p1[3], t3b, c3sum);
    const float S1  = t3b + s3b;

    float4* __restrict__ oA = reinterpret_cast<float4*>(out + (size_t)rowA * DCN_D);
    float4* __restrict__ oB = reinterpret_cast<float4*>(out + (size_t)rowB * DCN_D);
    #pragma unroll
    for (int j = 0; j < 4; ++j) {
        const int idx = lane + 64 * j;
        float4 a;
        a.x = fmaf(xa[j].x, S0, bv[j].x);
        a.y = fmaf(xa[j].y, S0, bv[j].y);
        a.z = fmaf(xa[j].z, S0, bv[j].z);
        a.w = fmaf(xa[j].w, S0, bv[j].w);
        oA[idx] = a;
        float4 c;
        c.x = fmaf(xb[j].x, S1, bv[j].x);
        c.y = fmaf(xb[j].y, S1, bv[j].y);
        c.z = fmaf(xb[j].z, S1, bv[j].z);
        c.w = fmaf(xb[j].w, S1, bv[j].w);
        oB[idx] = c;
    }
}

__global__ __launch_bounds__(256) void dcn_main_kernel(
    const float* __restrict__ x,
    const float* __restrict__ w,
    const float* __restrict__ ws,
    float* __restrict__ out,
    int B)
{
    const int wid  = (int)((blockIdx.x * 256u + threadIdx.x) >> 6);
    const int lane = (int)(threadIdx.x & 63);
    const int row0 = wid * 4;
    if (row0 >= B) return;

    const float4* __restrict__ w4  = reinterpret_cast<const float4*>(w);
    const float4* __restrict__ bs4 = reinterpret_cast<const float4*>(ws);

    // bias hoist (16 VGPR) + uniform scalars -- issued FIRST so later waits
    // on them don't drain the x queue
    float4 bv[4];
    #pragma unroll
    for (int j = 0; j < 4; ++j) bv[j] = bs4[lane + 64 * j];
    const float c01   = ws[DCN_D + 0];
    const float c2sum = ws[DCN_D + 1] + ws[DCN_D + 2];
    const float c3sum = ws[DCN_D + 3] + ws[DCN_D + 4] + ws[DCN_D + 5];

    // all 16 x-loads issued up-front: 16 KB in flight per wave
    float4 xv[4][4];
    #pragma unroll
    for (int r = 0; r < 4; ++r) {
        const float4* __restrict__ xr =
            reinterpret_cast<const float4*>(x + (size_t)(row0 + r) * DCN_D);
        #pragma unroll
        for (int j = 0; j < 4; ++j) xv[r][j] = xr[lane + 64 * j];
    }

    dcn_pair(xv[0], xv[1], w4, bv, c01, c2sum, c3sum, out, row0 + 0, row0 + 1, lane);
    dcn_pair(xv[2], xv[3], w4, bv, c01, c2sum, c3sum, out, row0 + 2, row0 + 3, lane);
}

extern "C" void kernel_launch(void* const* d_in, const int* in_sizes, int n_in,
                              void* d_out, int out_size, void* d_ws, size_t ws_size,
                              hipStream_t stream) {
    const float* x = (const float*)d_in[0];
    const float* w = (const float*)d_in[1];
    const float* b = (const float*)d_in[2];
    float* out = (float*)d_out;
    float* ws = (float*)d_ws;
    const int B = in_sizes[0] / DCN_D;

    dcn_pre_kernel<<<1, 256, 0, stream>>>(w, b, ws);
    // 4 rows per wave, 4 waves per block -> 16 rows per block
    const int rows_per_block = 16;
    dcn_main_kernel<<<(B + rows_per_block - 1) / rows_per_block, 256, 0, stream>>>(
        x, w, ws, out, B);
}